// Round 1
// baseline (1433.738 us; speedup 1.0000x reference)
//
#include <hip/hip_runtime.h>
#include <cstdint>

using u16 = unsigned short;
typedef __attribute__((ext_vector_type(8))) short bhalf8;
typedef __attribute__((ext_vector_type(4))) float floatx4;

// ---------- bf16 helpers (storage = ushort, round-to-nearest-even) ----------
__device__ __forceinline__ float bf2f(u16 u) {
  union { unsigned int i; float f; } v; v.i = ((unsigned int)u) << 16; return v.f;
}
__device__ __forceinline__ u16 f2bf(float f) {
  union { float f; unsigned int i; } v; v.f = f;
  unsigned int r = v.i + 0x7fffu + ((v.i >> 16) & 1u);
  return (u16)(r >> 16);
}

__device__ __forceinline__ void gload16(const void* g, void* l) {
  __builtin_amdgcn_global_load_lds((const __attribute__((address_space(1))) void*)g,
                                   (__attribute__((address_space(3))) void*)l, 16, 0, 0);
}

// ---------- weight transpose + relu + bf16 cast: W (K x N) f32 -> Wt (N x K) bf16 ----------
__global__ void wtrans_relu(const float* __restrict__ W, u16* __restrict__ Wt, int K, int N) {
  __shared__ float tile[32][33];
  const int tx = threadIdx.x & 31, ty = threadIdx.x >> 5;
  const int k0 = blockIdx.x * 32, n0 = blockIdx.y * 32;
#pragma unroll
  for (int r = 0; r < 4; ++r)
    tile[ty + r * 8][tx] = W[(size_t)(k0 + ty + r * 8) * N + n0 + tx];
  __syncthreads();
#pragma unroll
  for (int r = 0; r < 4; ++r)
    Wt[(size_t)(n0 + ty + r * 8) * K + k0 + tx] = f2bf(fmaxf(tile[tx][ty + r * 8], 0.f));
}

// ---------- input spike transpose: (B=128, I=1024, T=256) f32 -> (T*B, I) bf16 ----------
__global__ void spike_transpose(const float* __restrict__ sp, u16* __restrict__ S) {
  __shared__ float tile[32][33];
  const int tx = threadIdx.x & 31, ty = threadIdx.x >> 5;
  const int t0 = blockIdx.x * 32;   // T/32 = 8
  const int i0 = blockIdx.y * 32;   // I/32 = 32
  const int b  = blockIdx.z;        // 128
  const size_t I = 1024, T = 256, B = 128;
#pragma unroll
  for (int r = 0; r < 4; ++r)
    tile[ty + r * 8][tx] = sp[((size_t)b * I + i0 + ty + r * 8) * T + t0 + tx];
  __syncthreads();
#pragma unroll
  for (int r = 0; r < 4; ++r)
    S[((size_t)(t0 + ty + r * 8) * B + b) * I + i0 + tx] = f2bf(tile[tx][ty + r * 8]);
}

// ---------- bf16 MFMA GEMM: C (M x N) bf16 = A (M x K) bf16 * Bt^T, Bt is (N x K) bf16 ----------
// M = 32768 fixed by grid. 128x128 tile, BK=32, 4 waves (2x2), 16x16x32 MFMA.
// LDS layout [kgrp=4][row=128][8] -> conflict-free ds_read_b128 fragment reads,
// linear global_load_lds staging (wave-uniform LDS base + lane*16).
__global__ __launch_bounds__(256) void gemm_bf16(const u16* __restrict__ A,
                                                 const u16* __restrict__ Bt,
                                                 u16* __restrict__ C,
                                                 int K, int N) {
  __shared__ __align__(16) u16 As[4][128][8];
  __shared__ __align__(16) u16 Bs[4][128][8];
  const int tid  = threadIdx.x;
  const int lane = tid & 63;
  const int wave = tid >> 6;
  const int nTn  = N >> 7;
  const int mt   = blockIdx.x / nTn;
  const int nt   = blockIdx.x - mt * nTn;

  floatx4 acc[4][4];
#pragma unroll
  for (int i = 0; i < 4; ++i)
#pragma unroll
    for (int j = 0; j < 4; ++j)
      acc[i][j] = (floatx4){0.f, 0.f, 0.f, 0.f};

  const int wm = (wave >> 1) * 64;
  const int wn = (wave & 1) * 64;
  const int fr = lane & 15;   // fragment row/col within 16
  const int fg = lane >> 4;   // fragment k-group (0..3)

  // staging pointers: wave w stages k-group g=w for all 128 rows (2 issues of 64 rows)
  const u16* gA0 = A  + (size_t)(mt * 128 + lane) * K + wave * 8;
  const u16* gB0 = Bt + (size_t)(nt * 128 + lane) * K + wave * 8;
  u16* lA0 = &As[wave][0][0];
  u16* lA1 = &As[wave][64][0];
  u16* lB0 = &Bs[wave][0][0];
  u16* lB1 = &Bs[wave][64][0];

  for (int kt = 0; kt < K; kt += 32) {
    gload16(gA0 + kt, lA0);
    gload16(gA0 + kt + (size_t)64 * K, lA1);
    gload16(gB0 + kt, lB0);
    gload16(gB0 + kt + (size_t)64 * K, lB1);
    __syncthreads();   // drains vmcnt before reads

    bhalf8 af[4], bf[4];
#pragma unroll
    for (int i = 0; i < 4; ++i) {
      af[i] = *(const bhalf8*)(&As[fg][wm + i * 16 + fr][0]);
      bf[i] = *(const bhalf8*)(&Bs[fg][wn + i * 16 + fr][0]);
    }
#pragma unroll
    for (int i = 0; i < 4; ++i)
#pragma unroll
      for (int j = 0; j < 4; ++j)
        acc[i][j] = __builtin_amdgcn_mfma_f32_16x16x32_bf16(af[i], bf[j], acc[i][j], 0, 0, 0);
    __syncthreads();   // protect LDS before next stage
  }

  // C/D layout (m89-verified): col = lane&15, row = (lane>>4)*4 + reg
  const size_t rb = (size_t)(mt * 128 + wm + fg * 4);
  const size_t cb = (size_t)(nt * 128 + wn + fr);
#pragma unroll
  for (int i = 0; i < 4; ++i)
#pragma unroll
    for (int j = 0; j < 4; ++j)
#pragma unroll
      for (int r = 0; r < 4; ++r)
        C[(rb + i * 16 + r) * (size_t)N + cb + j * 16] = f2bf(acc[i][j][r]);
}

// ---------- LIF scan over T for one layer ----------
// Cur: (T*B, H) bf16 input current. out: (B, H, T) f32 spikes.
// sshift (optional): (T*B, H) bf16 spikes shifted by +1 timestep (slice 0 zeroed).
// rates (optional): (B*H) f32 mean firing rate.
__global__ __launch_bounds__(256) void lif_scan(const u16* __restrict__ Cur,
                                                float* __restrict__ out,
                                                u16* __restrict__ sshift,
                                                float* __restrict__ rates,
                                                int H) {
  const int gidx = blockIdx.x * 256 + threadIdx.x;  // = b*H + h, grid sized exactly
  const size_t BH = (size_t)128 * H;
  float v = -65.f;
  float ssum = 0.f;
  if (sshift) sshift[gidx] = 0;  // t=0 slice: s_init = 0
  float buf[16];
  for (int t0 = 0; t0 < 256; t0 += 16) {
#pragma unroll
    for (int j = 0; j < 16; ++j) {
      const int t = t0 + j;
      const float c  = bf2f(Cur[(size_t)t * BH + gidx]);
      const float vn = v + 0.05f * ((-65.f - v) + c);   // v + (DT/TAU)*((V_REST - v) + cur)
      const float s  = (vn >= -50.f) ? 1.f : 0.f;       // spike(v_new - V_TH)
      v = vn - s * (vn + 65.f);                         // faithful soft reset
      ssum += s;
      buf[j] = s;
      if (sshift && t < 255)
        sshift[(size_t)(t + 1) * BH + gidx] = (u16)((s != 0.f) ? 0x3F80u : 0u);
    }
    float* o = out + (size_t)gidx * 256 + t0;
#pragma unroll
    for (int q = 0; q < 4; ++q) {
      float4 w;
      w.x = buf[q * 4 + 0]; w.y = buf[q * 4 + 1];
      w.z = buf[q * 4 + 2]; w.w = buf[q * 4 + 3];
      *(float4*)(o + q * 4) = w;
    }
  }
  if (rates) rates[gidx] = ssum * (1.f / 256.f);
}

// ---------- launch ----------
extern "C" void kernel_launch(void* const* d_in, const int* in_sizes, int n_in,
                              void* d_out, int out_size, void* d_ws, size_t ws_size,
                              hipStream_t stream) {
  const float* w0 = (const float*)d_in[0];  // 1024x1024
  const float* w1 = (const float*)d_in[1];  // 1024x1024
  const float* w2 = (const float*)d_in[2];  // 1024x512
  const float* w3 = (const float*)d_in[3];  // 512x256
  const float* w4 = (const float*)d_in[4];  // 256x128
  const float* spikes = (const float*)d_in[5];  // (128, 1024, 256)

  uint8_t* ws = (uint8_t*)d_ws;
  u16* S0 = (u16*)(ws + 0);            // 32768x1024 bf16 = 64 MiB (input spikes ^T / shift ping)
  u16* S1 = (u16*)(ws + 67108864);     // 64 MiB (shift pong)
  u16* Cb = (u16*)(ws + 134217728);    // 64 MiB (bf16 current, reused per layer)
  u16* W0 = (u16*)(ws + 201326592);    // 2 MiB
  u16* W1 = (u16*)(ws + 203423744);    // 2 MiB
  u16* W2 = (u16*)(ws + 205520896);    // 1 MiB
  u16* W3 = (u16*)(ws + 206569472);    // 256 KiB
  u16* W4 = (u16*)(ws + 206831616);    // 64 KiB

  float* out0  = (float*)d_out;            // (128,1024,256)
  float* out1  = out0 + 33554432;          // (128,1024,256)
  float* out2  = out0 + 67108864;          // (128, 512,256)
  float* out3  = out0 + 83886080;          // (128, 256,256)
  float* out4  = out0 + 92274688;          // (128, 128,256)
  float* rates = out0 + 96468992;          // (128,128)

  // 1) weights: transpose + relu + bf16
  wtrans_relu<<<dim3(32, 32), 256, 0, stream>>>(w0, W0, 1024, 1024);
  wtrans_relu<<<dim3(32, 32), 256, 0, stream>>>(w1, W1, 1024, 1024);
  wtrans_relu<<<dim3(32, 16), 256, 0, stream>>>(w2, W2, 1024, 512);
  wtrans_relu<<<dim3(16,  8), 256, 0, stream>>>(w3, W3, 512, 256);
  wtrans_relu<<<dim3( 8,  4), 256, 0, stream>>>(w4, W4, 256, 128);

  // 2) input spikes -> (T*B, 1024) bf16
  spike_transpose<<<dim3(8, 32, 128), 256, 0, stream>>>(spikes, S0);

  // 3) layer pipeline: gemm -> lif (ping-pong shifted-spike buffers)
  gemm_bf16<<<256 * 8, 256, 0, stream>>>(S0, W0, Cb, 1024, 1024);
  lif_scan<<<512, 256, 0, stream>>>(Cb, out0, S1, nullptr, 1024);

  gemm_bf16<<<256 * 8, 256, 0, stream>>>(S1, W1, Cb, 1024, 1024);
  lif_scan<<<512, 256, 0, stream>>>(Cb, out1, S0, nullptr, 1024);

  gemm_bf16<<<256 * 4, 256, 0, stream>>>(S0, W2, Cb, 1024, 512);
  lif_scan<<<256, 256, 0, stream>>>(Cb, out2, S1, nullptr, 512);

  gemm_bf16<<<256 * 2, 256, 0, stream>>>(S1, W3, Cb, 512, 256);
  lif_scan<<<128, 256, 0, stream>>>(Cb, out3, S0, nullptr, 256);

  gemm_bf16<<<256 * 1, 256, 0, stream>>>(S0, W4, Cb, 256, 128);
  lif_scan<<<64, 256, 0, stream>>>(Cb, out4, nullptr, rates, 128);
}

// Round 10
// 948.804 us; speedup vs baseline: 1.5111x; 1.5111x over previous
//
#include <hip/hip_runtime.h>
#include <cstdint>

using u16 = unsigned short;
using u32 = unsigned int;
typedef __attribute__((ext_vector_type(8))) short bhalf8;
typedef __attribute__((ext_vector_type(4))) float floatx4;

// ---------- bf16 helpers (storage = ushort, round-to-nearest-even) ----------
__device__ __forceinline__ float bf2f(u16 u) {
  union { unsigned int i; float f; } v; v.i = ((unsigned int)u) << 16; return v.f;
}
__device__ __forceinline__ u16 f2bf(float f) {
  union { float f; unsigned int i; } v; v.f = f;
  unsigned int r = v.i + 0x7fffu + ((v.i >> 16) & 1u);
  return (u16)(r >> 16);
}

__device__ __forceinline__ void gload16(const void* g, void* l) {
  __builtin_amdgcn_global_load_lds((const __attribute__((address_space(1))) void*)g,
                                   (__attribute__((address_space(3))) void*)l, 16, 0, 0);
}

// ---------- zero the per-layer activity flag arrays (ws is poisoned 0xAA) ----------
__global__ void zero_flags(u32* __restrict__ flags) {
  flags[threadIdx.x] = 0u;   // 64 words = 4 layers x 16
}

// ---------- weight transpose + relu + bf16 cast: W (K x N) f32 -> Wt (N x K) bf16 ----------
__global__ void wtrans_relu(const float* __restrict__ W, u16* __restrict__ Wt, int K, int N) {
  __shared__ float tile[32][33];
  const int tx = threadIdx.x & 31, ty = threadIdx.x >> 5;
  const int k0 = blockIdx.x * 32, n0 = blockIdx.y * 32;
#pragma unroll
  for (int r = 0; r < 4; ++r)
    tile[ty + r * 8][tx] = W[(size_t)(k0 + ty + r * 8) * N + n0 + tx];
  __syncthreads();
#pragma unroll
  for (int r = 0; r < 4; ++r)
    Wt[(size_t)(n0 + ty + r * 8) * K + k0 + tx] = f2bf(fmaxf(tile[tx][ty + r * 8], 0.f));
}

// ---------- input spike transpose: (B=128, I=1024, T=256) f32 -> (T*B, I) bf16 ----------
__global__ void spike_transpose(const float* __restrict__ sp, u16* __restrict__ S) {
  __shared__ float tile[32][33];
  const int tx = threadIdx.x & 31, ty = threadIdx.x >> 5;
  const int t0 = blockIdx.x * 32;   // T/32 = 8
  const int i0 = blockIdx.y * 32;   // I/32 = 32
  const int b  = blockIdx.z;        // 128
  const size_t I = 1024, T = 256;
#pragma unroll
  for (int r = 0; r < 4; ++r)
    tile[ty + r * 8][tx] = sp[((size_t)b * I + i0 + ty + r * 8) * T + t0 + tx];
  __syncthreads();
#pragma unroll
  for (int r = 0; r < 4; ++r)
    S[((size_t)(t0 + ty + r * 8) * 128 + b) * I + i0 + tx] = f2bf(tile[tx][ty + r * 8]);
}

// ---------- bf16 MFMA GEMM: C (M x N) bf16 = A (M x K) bf16 * Bt^T, Bt is (N x K) bf16 ----------
// M = 32768 fixed by grid. 128x128 tile, BK=32, 4 waves (2x2), 16x16x32 MFMA.
// Row-panel mt == timestep t (B=128): if flags && bit mt clear -> whole panel of A is
// zero spikes -> C tile would be zero -> skip everything (consumer substitutes c=0).
__global__ __launch_bounds__(256) void gemm_bf16(const u16* __restrict__ A,
                                                 const u16* __restrict__ Bt,
                                                 u16* __restrict__ C,
                                                 int K, int N,
                                                 const u32* __restrict__ flags) {
  __shared__ __align__(16) u16 As[4][128][8];
  __shared__ __align__(16) u16 Bs[4][128][8];
  const int tid  = threadIdx.x;
  const int lane = tid & 63;
  const int wave = tid >> 6;
  const int nTn  = N >> 7;
  const int mt   = blockIdx.x / nTn;
  const int nt   = blockIdx.x - mt * nTn;

  if (flags && (((flags[mt >> 5] >> (mt & 31)) & 1u) == 0u)) return;

  floatx4 acc[4][4];
#pragma unroll
  for (int i = 0; i < 4; ++i)
#pragma unroll
    for (int j = 0; j < 4; ++j)
      acc[i][j] = (floatx4){0.f, 0.f, 0.f, 0.f};

  const int wm = (wave >> 1) * 64;
  const int wn = (wave & 1) * 64;
  const int fr = lane & 15;   // fragment row/col within 16
  const int fg = lane >> 4;   // fragment k-group (0..3)

  const u16* gA0 = A  + (size_t)(mt * 128 + lane) * K + wave * 8;
  const u16* gB0 = Bt + (size_t)(nt * 128 + lane) * K + wave * 8;
  u16* lA0 = &As[wave][0][0];
  u16* lA1 = &As[wave][64][0];
  u16* lB0 = &Bs[wave][0][0];
  u16* lB1 = &Bs[wave][64][0];

  for (int kt = 0; kt < K; kt += 32) {
    gload16(gA0 + kt, lA0);
    gload16(gA0 + kt + (size_t)64 * K, lA1);
    gload16(gB0 + kt, lB0);
    gload16(gB0 + kt + (size_t)64 * K, lB1);
    __syncthreads();

    bhalf8 af[4], bf[4];
#pragma unroll
    for (int i = 0; i < 4; ++i) {
      af[i] = *(const bhalf8*)(&As[fg][wm + i * 16 + fr][0]);
      bf[i] = *(const bhalf8*)(&Bs[fg][wn + i * 16 + fr][0]);
    }
#pragma unroll
    for (int i = 0; i < 4; ++i)
#pragma unroll
      for (int j = 0; j < 4; ++j)
        acc[i][j] = __builtin_amdgcn_mfma_f32_16x16x32_bf16(af[i], bf[j], acc[i][j], 0, 0, 0);
    __syncthreads();
  }

  // C/D layout: col = lane&15, row = (lane>>4)*4 + reg
  const size_t rb = (size_t)(mt * 128 + wm + fg * 4);
  const size_t cb = (size_t)(nt * 128 + wn + fr);
#pragma unroll
  for (int i = 0; i < 4; ++i)
#pragma unroll
    for (int j = 0; j < 4; ++j)
#pragma unroll
      for (int r = 0; r < 4; ++r)
        C[(rb + i * 16 + r) * (size_t)N + cb + j * 16] = f2bf(acc[i][j][r]);
}

// ---------- LIF scan over T for one layer ----------
// Cur: (T*B, H) bf16 current (valid only where aflag bit t set; else treated as 0).
// out: (B, H, T) f32 spikes. sshift: (T*B, H) bf16 spikes shifted +1 step.
// oflag: next layer's activity bitmask (bit t+1 = any spike at t).
// rates: (B*H) f32 mean rate.
__global__ __launch_bounds__(256) void lif_scan(const u16* __restrict__ Cur,
                                                const u32* __restrict__ aflag,
                                                float* __restrict__ out,
                                                u16* __restrict__ sshift,
                                                u32* __restrict__ oflag,
                                                float* __restrict__ rates,
                                                int H) {
  const int gidx = blockIdx.x * 256 + threadIdx.x;  // = b*H + h
  const size_t BH = (size_t)128 * H;
  u32 fw[8];
#pragma unroll
  for (int w = 0; w < 8; ++w) fw[w] = aflag ? aflag[w] : 0xffffffffu;

  float v = -65.f;
  float ssum = 0.f;
  if (sshift) sshift[gidx] = 0;  // t=0 slice: s_init = 0
  float buf[16];
  for (int t0 = 0; t0 < 256; t0 += 16) {
    u32 wavemask = 0;
#pragma unroll
    for (int j = 0; j < 16; ++j) {
      const int t = t0 + j;
      const bool act = ((fw[t >> 5] >> (t & 31)) & 1u) != 0u;
      const float c  = act ? bf2f(Cur[(size_t)t * BH + gidx]) : 0.f;
      const float vn = v + 0.05f * ((-65.f - v) + c);   // v + (DT/TAU)*((V_REST - v) + cur)
      const float s  = (vn >= -50.f) ? 1.f : 0.f;       // spike(v_new - V_TH)
      v = vn - s * (vn + 65.f);                         // soft reset
      ssum += s;
      buf[j] = s;
      if (sshift && t < 255)
        sshift[(size_t)(t + 1) * BH + gidx] = (u16)((s != 0.f) ? 0x3F80u : 0u);
      if (oflag) {
        if (__ballot(s != 0.f) != 0ull) wavemask |= (1u << j);
      }
    }
    if (t0 == 240) wavemask &= 0x7fffu;   // t=255 spikes have no next step
    if (oflag && wavemask && ((threadIdx.x & 63) == 0)) {
      const unsigned long long m = (unsigned long long)wavemask << ((t0 + 1) & 31);
      const int w = (t0 + 1) >> 5;
      if ((u32)m) atomicOr(&oflag[w], (u32)m);
      if (m >> 32) atomicOr(&oflag[w + 1], (u32)(m >> 32));
    }
    float* o = out + (size_t)gidx * 256 + t0;
#pragma unroll
    for (int q = 0; q < 4; ++q) {
      float4 wv;
      wv.x = buf[q * 4 + 0]; wv.y = buf[q * 4 + 1];
      wv.z = buf[q * 4 + 2]; wv.w = buf[q * 4 + 3];
      *(float4*)(o + q * 4) = wv;
    }
  }
  if (rates) rates[gidx] = ssum * (1.f / 256.f);
}

// ---------- launch ----------
extern "C" void kernel_launch(void* const* d_in, const int* in_sizes, int n_in,
                              void* d_out, int out_size, void* d_ws, size_t ws_size,
                              hipStream_t stream) {
  const float* w0 = (const float*)d_in[0];  // 1024x1024
  const float* w1 = (const float*)d_in[1];  // 1024x1024
  const float* w2 = (const float*)d_in[2];  // 1024x512
  const float* w3 = (const float*)d_in[3];  // 512x256
  const float* w4 = (const float*)d_in[4];  // 256x128
  const float* spikes = (const float*)d_in[5];  // (128, 1024, 256)

  uint8_t* ws = (uint8_t*)d_ws;
  u16* S0 = (u16*)(ws + 0);            // 64 MiB (input spikes^T / shift ping)
  u16* S1 = (u16*)(ws + 67108864);     // 64 MiB (shift pong)
  u16* Cb = (u16*)(ws + 134217728);    // 64 MiB (bf16 current, reused per layer)
  u16* W0 = (u16*)(ws + 201326592);    // 2 MiB
  u16* W1 = (u16*)(ws + 203423744);    // 2 MiB
  u16* W2 = (u16*)(ws + 205520896);    // 1 MiB
  u16* W3 = (u16*)(ws + 206569472);    // 256 KiB
  u16* W4 = (u16*)(ws + 206831616);    // 64 KiB
  u32* FL = (u32*)(ws + 206897152);    // 64 u32: 4 layers x 16
  u32* F1 = FL +  0;
  u32* F2 = FL + 16;
  u32* F3 = FL + 32;
  u32* F4 = FL + 48;

  float* out0  = (float*)d_out;            // (128,1024,256)
  float* out1  = out0 + 33554432;          // (128,1024,256)
  float* out2  = out0 + 67108864;          // (128, 512,256)
  float* out3  = out0 + 83886080;          // (128, 256,256)
  float* out4  = out0 + 92274688;          // (128, 128,256)
  float* rates = out0 + 96468992;          // (128,128)

  zero_flags<<<1, 64, 0, stream>>>(FL);

  // 1) weights: transpose + relu + bf16
  wtrans_relu<<<dim3(32, 32), 256, 0, stream>>>(w0, W0, 1024, 1024);
  wtrans_relu<<<dim3(32, 32), 256, 0, stream>>>(w1, W1, 1024, 1024);
  wtrans_relu<<<dim3(32, 16), 256, 0, stream>>>(w2, W2, 1024, 512);
  wtrans_relu<<<dim3(16,  8), 256, 0, stream>>>(w3, W3, 512, 256);
  wtrans_relu<<<dim3( 8,  4), 256, 0, stream>>>(w4, W4, 256, 128);

  // 2) input spikes -> (T*B, 1024) bf16
  spike_transpose<<<dim3(8, 32, 128), 256, 0, stream>>>(spikes, S0);

  // 3) layer pipeline: gemm -> lif, activity-gated per timestep panel
  gemm_bf16<<<256 * 8, 256, 0, stream>>>(S0, W0, Cb, 1024, 1024, nullptr);
  lif_scan<<<512, 256, 0, stream>>>(Cb, nullptr, out0, S1, F1, nullptr, 1024);

  gemm_bf16<<<256 * 8, 256, 0, stream>>>(S1, W1, Cb, 1024, 1024, F1);
  lif_scan<<<512, 256, 0, stream>>>(Cb, F1, out1, S0, F2, nullptr, 1024);

  gemm_bf16<<<256 * 4, 256, 0, stream>>>(S0, W2, Cb, 1024, 512, F2);
  lif_scan<<<256, 256, 0, stream>>>(Cb, F2, out2, S1, F3, nullptr, 512);

  gemm_bf16<<<256 * 2, 256, 0, stream>>>(S1, W3, Cb, 512, 256, F3);
  lif_scan<<<128, 256, 0, stream>>>(Cb, F3, out3, S0, F4, nullptr, 256);

  gemm_bf16<<<256 * 1, 256, 0, stream>>>(S0, W4, Cb, 256, 128, F4);
  lif_scan<<<64, 256, 0, stream>>>(Cb, F4, out4, nullptr, nullptr, rates, 128);
}

// Round 11
// 861.744 us; speedup vs baseline: 1.6638x; 1.1010x over previous
//
#include <hip/hip_runtime.h>
#include <cstdint>

using u16 = unsigned short;
using u32 = unsigned int;
typedef __attribute__((ext_vector_type(8))) short bhalf8;
typedef __attribute__((ext_vector_type(4))) float floatx4;

// ---------- bf16 helpers (storage = ushort, round-to-nearest-even) ----------
__device__ __forceinline__ float bf2f(u16 u) {
  union { unsigned int i; float f; } v; v.i = ((unsigned int)u) << 16; return v.f;
}
__device__ __forceinline__ u16 f2bf(float f) {
  union { float f; unsigned int i; } v; v.f = f;
  unsigned int r = v.i + 0x7fffu + ((v.i >> 16) & 1u);
  return (u16)(r >> 16);
}

__device__ __forceinline__ void gload16(const void* g, void* l) {
  __builtin_amdgcn_global_load_lds((const __attribute__((address_space(1))) void*)g,
                                   (__attribute__((address_space(3))) void*)l, 16, 0, 0);
}

// ---------- fused weight prep: 5x (transpose + relu + bf16) + flag zeroing ----------
// One launch replaces 5 wtrans_relu + zero_flags. Segments (32x32 tiles, row-major
// over (K/32, N/32)): w0 1024, w1 1024, w2 512, w3 128, w4 32 -> cum 1024,2048,2560,
// 2688,2720; block 2720 zeroes the 64 flag words.
__global__ __launch_bounds__(256) void prep_weights(
    const float* __restrict__ w0, const float* __restrict__ w1,
    const float* __restrict__ w2, const float* __restrict__ w3,
    const float* __restrict__ w4,
    u16* __restrict__ W0, u16* __restrict__ W1, u16* __restrict__ W2,
    u16* __restrict__ W3, u16* __restrict__ W4, u32* __restrict__ flags) {
  const int bid = blockIdx.x;
  const int tid = threadIdx.x;
  if (bid >= 2720) {
    if (tid < 64) flags[tid] = 0u;   // 4 layers x 16 words
    return;
  }
  const float* W; u16* Wt; int K, N, rel;
  if (bid < 1024)      { W = w0; Wt = W0; K = 1024; N = 1024; rel = bid; }
  else if (bid < 2048) { W = w1; Wt = W1; K = 1024; N = 1024; rel = bid - 1024; }
  else if (bid < 2560) { W = w2; Wt = W2; K = 1024; N =  512; rel = bid - 2048; }
  else if (bid < 2688) { W = w3; Wt = W3; K =  512; N =  256; rel = bid - 2560; }
  else                 { W = w4; Wt = W4; K =  256; N =  128; rel = bid - 2688; }
  const int nx = K >> 5;
  const int k0 = (rel % nx) * 32;
  const int n0 = (rel / nx) * 32;

  __shared__ float tile[32][33];
  const int tx = tid & 31, ty = tid >> 5;
#pragma unroll
  for (int r = 0; r < 4; ++r)
    tile[ty + r * 8][tx] = W[(size_t)(k0 + ty + r * 8) * N + n0 + tx];
  __syncthreads();
#pragma unroll
  for (int r = 0; r < 4; ++r)
    Wt[(size_t)(n0 + ty + r * 8) * K + k0 + tx] = f2bf(fmaxf(tile[tx][ty + r * 8], 0.f));
}

// ---------- input spike transpose: (B=128, I=1024, T=256) f32 -> (T*B, I) bf16 ----------
__global__ void spike_transpose(const float* __restrict__ sp, u16* __restrict__ S) {
  __shared__ float tile[32][33];
  const int tx = threadIdx.x & 31, ty = threadIdx.x >> 5;
  const int t0 = blockIdx.x * 32;   // T/32 = 8
  const int i0 = blockIdx.y * 32;   // I/32 = 32
  const int b  = blockIdx.z;        // 128
  const size_t I = 1024, T = 256;
#pragma unroll
  for (int r = 0; r < 4; ++r)
    tile[ty + r * 8][tx] = sp[((size_t)b * I + i0 + ty + r * 8) * T + t0 + tx];
  __syncthreads();
#pragma unroll
  for (int r = 0; r < 4; ++r)
    S[((size_t)(t0 + ty + r * 8) * 128 + b) * I + i0 + tx] = f2bf(tile[tx][ty + r * 8]);
}

// ---------- bf16 MFMA GEMM: C (M x N) bf16 = A (M x K) bf16 * Bt^T, Bt is (N x K) bf16 ----------
// M = 32768 fixed by grid. 128x128 tile, BK=32, 4 waves (2x2), 16x16x32 MFMA.
// Row-panel mt == timestep t (B=128): if flags && bit mt clear -> whole panel of A is
// zero spikes -> C tile would be zero -> skip everything (consumer substitutes c=0).
__global__ __launch_bounds__(256) void gemm_bf16(const u16* __restrict__ A,
                                                 const u16* __restrict__ Bt,
                                                 u16* __restrict__ C,
                                                 int K, int N,
                                                 const u32* __restrict__ flags) {
  __shared__ __align__(16) u16 As[4][128][8];
  __shared__ __align__(16) u16 Bs[4][128][8];
  const int tid  = threadIdx.x;
  const int lane = tid & 63;
  const int wave = tid >> 6;
  const int nTn  = N >> 7;
  const int mt   = blockIdx.x / nTn;
  const int nt   = blockIdx.x - mt * nTn;

  if (flags && (((flags[mt >> 5] >> (mt & 31)) & 1u) == 0u)) return;

  floatx4 acc[4][4];
#pragma unroll
  for (int i = 0; i < 4; ++i)
#pragma unroll
    for (int j = 0; j < 4; ++j)
      acc[i][j] = (floatx4){0.f, 0.f, 0.f, 0.f};

  const int wm = (wave >> 1) * 64;
  const int wn = (wave & 1) * 64;
  const int fr = lane & 15;   // fragment row/col within 16
  const int fg = lane >> 4;   // fragment k-group (0..3)

  const u16* gA0 = A  + (size_t)(mt * 128 + lane) * K + wave * 8;
  const u16* gB0 = Bt + (size_t)(nt * 128 + lane) * K + wave * 8;
  u16* lA0 = &As[wave][0][0];
  u16* lA1 = &As[wave][64][0];
  u16* lB0 = &Bs[wave][0][0];
  u16* lB1 = &Bs[wave][64][0];

  for (int kt = 0; kt < K; kt += 32) {
    gload16(gA0 + kt, lA0);
    gload16(gA0 + kt + (size_t)64 * K, lA1);
    gload16(gB0 + kt, lB0);
    gload16(gB0 + kt + (size_t)64 * K, lB1);
    __syncthreads();

    bhalf8 af[4], bf[4];
#pragma unroll
    for (int i = 0; i < 4; ++i) {
      af[i] = *(const bhalf8*)(&As[fg][wm + i * 16 + fr][0]);
      bf[i] = *(const bhalf8*)(&Bs[fg][wn + i * 16 + fr][0]);
    }
#pragma unroll
    for (int i = 0; i < 4; ++i)
#pragma unroll
      for (int j = 0; j < 4; ++j)
        acc[i][j] = __builtin_amdgcn_mfma_f32_16x16x32_bf16(af[i], bf[j], acc[i][j], 0, 0, 0);
    __syncthreads();
  }

  // C/D layout: col = lane&15, row = (lane>>4)*4 + reg
  const size_t rb = (size_t)(mt * 128 + wm + fg * 4);
  const size_t cb = (size_t)(nt * 128 + wn + fr);
#pragma unroll
  for (int i = 0; i < 4; ++i)
#pragma unroll
    for (int j = 0; j < 4; ++j)
#pragma unroll
      for (int r = 0; r < 4; ++r)
        C[(rb + i * 16 + r) * (size_t)N + cb + j * 16] = f2bf(acc[i][j][r]);
}

// ---------- LIF scan over T for one layer ----------
// Cur: (T*B, H) bf16 current (valid only where aflag bit t set; else treated as 0).
// out: (B, H, T) f32 spikes. sshift: (T*B, H) bf16 spikes shifted +1 step.
// oflag: next layer's activity bitmask (bit t+1 = any spike at t).
// rates: (B*H) f32 mean rate.
// Fast path: if aflag present and ALL zero, the layer provably never spikes
// (c=0 for all t keeps v at exactly -65): write zero outputs, skip sshift
// entirely (the buffer is only read by a GEMM that the zero flags skip).
__global__ __launch_bounds__(256) void lif_scan(const u16* __restrict__ Cur,
                                                const u32* __restrict__ aflag,
                                                float* __restrict__ out,
                                                u16* __restrict__ sshift,
                                                u32* __restrict__ oflag,
                                                float* __restrict__ rates,
                                                int H) {
  const int gidx = blockIdx.x * 256 + threadIdx.x;  // = b*H + h
  const size_t BH = (size_t)128 * H;
  u32 fw[8];
  u32 any = 0;
#pragma unroll
  for (int w = 0; w < 8; ++w) {
    fw[w] = aflag ? aflag[w] : 0xffffffffu;
    any |= fw[w];
  }

  if (any == 0u) {   // block-uniform: silent layer
    const float4 z = {0.f, 0.f, 0.f, 0.f};
    float* o = out + (size_t)gidx * 256;
#pragma unroll
    for (int q = 0; q < 64; ++q) *(float4*)(o + q * 4) = z;
    if (rates) rates[gidx] = 0.f;
    return;
  }

  float v = -65.f;
  float ssum = 0.f;
  if (sshift) sshift[gidx] = 0;  // t=0 slice: s_init = 0
  float buf[16];
  for (int t0 = 0; t0 < 256; t0 += 16) {
    u32 wavemask = 0;
#pragma unroll
    for (int j = 0; j < 16; ++j) {
      const int t = t0 + j;
      const bool act = ((fw[t >> 5] >> (t & 31)) & 1u) != 0u;
      const float c  = act ? bf2f(Cur[(size_t)t * BH + gidx]) : 0.f;
      const float vn = v + 0.05f * ((-65.f - v) + c);   // v + (DT/TAU)*((V_REST - v) + cur)
      const float s  = (vn >= -50.f) ? 1.f : 0.f;       // spike(v_new - V_TH)
      v = vn - s * (vn + 65.f);                         // soft reset
      ssum += s;
      buf[j] = s;
      if (sshift && t < 255)
        sshift[(size_t)(t + 1) * BH + gidx] = (u16)((s != 0.f) ? 0x3F80u : 0u);
      if (oflag) {
        if (__ballot(s != 0.f) != 0ull) wavemask |= (1u << j);
      }
    }
    if (t0 == 240) wavemask &= 0x7fffu;   // t=255 spikes have no next step
    if (oflag && wavemask && ((threadIdx.x & 63) == 0)) {
      const unsigned long long m = (unsigned long long)wavemask << ((t0 + 1) & 31);
      const int w = (t0 + 1) >> 5;
      if ((u32)m) atomicOr(&oflag[w], (u32)m);
      if (m >> 32) atomicOr(&oflag[w + 1], (u32)(m >> 32));
    }
    float* o = out + (size_t)gidx * 256 + t0;
#pragma unroll
    for (int q = 0; q < 4; ++q) {
      float4 wv;
      wv.x = buf[q * 4 + 0]; wv.y = buf[q * 4 + 1];
      wv.z = buf[q * 4 + 2]; wv.w = buf[q * 4 + 3];
      *(float4*)(o + q * 4) = wv;
    }
  }
  if (rates) rates[gidx] = ssum * (1.f / 256.f);
}

// ---------- launch ----------
extern "C" void kernel_launch(void* const* d_in, const int* in_sizes, int n_in,
                              void* d_out, int out_size, void* d_ws, size_t ws_size,
                              hipStream_t stream) {
  const float* w0 = (const float*)d_in[0];  // 1024x1024
  const float* w1 = (const float*)d_in[1];  // 1024x1024
  const float* w2 = (const float*)d_in[2];  // 1024x512
  const float* w3 = (const float*)d_in[3];  // 512x256
  const float* w4 = (const float*)d_in[4];  // 256x128
  const float* spikes = (const float*)d_in[5];  // (128, 1024, 256)

  uint8_t* ws = (uint8_t*)d_ws;
  u16* S0 = (u16*)(ws + 0);            // 64 MiB (input spikes^T / shift ping)
  u16* S1 = (u16*)(ws + 67108864);     // 64 MiB (shift pong)
  u16* Cb = (u16*)(ws + 134217728);    // 64 MiB (bf16 current, reused per layer)
  u16* W0 = (u16*)(ws + 201326592);    // 2 MiB
  u16* W1 = (u16*)(ws + 203423744);    // 2 MiB
  u16* W2 = (u16*)(ws + 205520896);    // 1 MiB
  u16* W3 = (u16*)(ws + 206569472);    // 256 KiB
  u16* W4 = (u16*)(ws + 206831616);    // 64 KiB
  u32* FL = (u32*)(ws + 206897152);    // 64 u32: 4 layers x 16
  u32* F1 = FL +  0;
  u32* F2 = FL + 16;
  u32* F3 = FL + 32;
  u32* F4 = FL + 48;

  float* out0  = (float*)d_out;            // (128,1024,256)
  float* out1  = out0 + 33554432;          // (128,1024,256)
  float* out2  = out0 + 67108864;          // (128, 512,256)
  float* out3  = out0 + 83886080;          // (128, 256,256)
  float* out4  = out0 + 92274688;          // (128, 128,256)
  float* rates = out0 + 96468992;          // (128,128)

  // 1) fused weight prep (5 transposes + flag zeroing)
  prep_weights<<<2721, 256, 0, stream>>>(w0, w1, w2, w3, w4, W0, W1, W2, W3, W4, FL);

  // 2) input spikes -> (T*B, 1024) bf16
  spike_transpose<<<dim3(8, 32, 128), 256, 0, stream>>>(spikes, S0);

  // 3) layer pipeline: gemm -> lif, activity-gated per timestep panel
  gemm_bf16<<<256 * 8, 256, 0, stream>>>(S0, W0, Cb, 1024, 1024, nullptr);
  lif_scan<<<512, 256, 0, stream>>>(Cb, nullptr, out0, S1, F1, nullptr, 1024);

  gemm_bf16<<<256 * 8, 256, 0, stream>>>(S1, W1, Cb, 1024, 1024, F1);
  lif_scan<<<512, 256, 0, stream>>>(Cb, F1, out1, S0, F2, nullptr, 1024);

  gemm_bf16<<<256 * 4, 256, 0, stream>>>(S0, W2, Cb, 1024, 512, F2);
  lif_scan<<<256, 256, 0, stream>>>(Cb, F2, out2, S1, F3, nullptr, 512);

  gemm_bf16<<<256 * 2, 256, 0, stream>>>(S1, W3, Cb, 512, 256, F3);
  lif_scan<<<128, 256, 0, stream>>>(Cb, F3, out3, S0, F4, nullptr, 256);

  gemm_bf16<<<256 * 1, 256, 0, stream>>>(S0, W4, Cb, 256, 128, F4);
  lif_scan<<<64, 256, 0, stream>>>(Cb, F4, out4, nullptr, nullptr, rates, 128);
}

// Round 12
// 790.497 us; speedup vs baseline: 1.8137x; 1.0901x over previous
//
#include <hip/hip_runtime.h>
#include <cstdint>

using u16 = unsigned short;
using u32 = unsigned int;
typedef __attribute__((ext_vector_type(8))) short bhalf8;
typedef __attribute__((ext_vector_type(4))) float floatx4;

// ---------- bf16 helpers (storage = ushort, round-to-nearest-even) ----------
__device__ __forceinline__ float bf2f(u16 u) {
  union { unsigned int i; float f; } v; v.i = ((unsigned int)u) << 16; return v.f;
}
__device__ __forceinline__ u16 f2bf(float f) {
  union { float f; unsigned int i; } v; v.f = f;
  unsigned int r = v.i + 0x7fffu + ((v.i >> 16) & 1u);
  return (u16)(r >> 16);
}

__device__ __forceinline__ void gload16(const void* g, void* l) {
  __builtin_amdgcn_global_load_lds((const __attribute__((address_space(1))) void*)g,
                                   (__attribute__((address_space(3))) void*)l, 16, 0, 0);
}

// ---------- fused weight prep: 5x (transpose + relu + bf16) + flag zeroing ----------
__global__ __launch_bounds__(256) void prep_weights(
    const float* __restrict__ w0, const float* __restrict__ w1,
    const float* __restrict__ w2, const float* __restrict__ w3,
    const float* __restrict__ w4,
    u16* __restrict__ W0, u16* __restrict__ W1, u16* __restrict__ W2,
    u16* __restrict__ W3, u16* __restrict__ W4, u32* __restrict__ flags) {
  const int bid = blockIdx.x;
  const int tid = threadIdx.x;
  if (bid >= 2720) {
    if (tid < 64) flags[tid] = 0u;   // 4 layers x 16 words
    return;
  }
  const float* W; u16* Wt; int K, N, rel;
  if (bid < 1024)      { W = w0; Wt = W0; K = 1024; N = 1024; rel = bid; }
  else if (bid < 2048) { W = w1; Wt = W1; K = 1024; N = 1024; rel = bid - 1024; }
  else if (bid < 2560) { W = w2; Wt = W2; K = 1024; N =  512; rel = bid - 2048; }
  else if (bid < 2688) { W = w3; Wt = W3; K =  512; N =  256; rel = bid - 2560; }
  else                 { W = w4; Wt = W4; K =  256; N =  128; rel = bid - 2688; }
  const int nx = K >> 5;
  const int k0 = (rel % nx) * 32;
  const int n0 = (rel / nx) * 32;

  __shared__ float tile[32][33];
  const int tx = tid & 31, ty = tid >> 5;
#pragma unroll
  for (int r = 0; r < 4; ++r)
    tile[ty + r * 8][tx] = W[(size_t)(k0 + ty + r * 8) * N + n0 + tx];
  __syncthreads();
#pragma unroll
  for (int r = 0; r < 4; ++r)
    Wt[(size_t)(n0 + ty + r * 8) * K + k0 + tx] = f2bf(fmaxf(tile[tx][ty + r * 8], 0.f));
}

// ---------- input spike transpose: (B=128, I=1024, T=256) f32 -> (T*B, I) bf16 ----------
__global__ void spike_transpose(const float* __restrict__ sp, u16* __restrict__ S) {
  __shared__ float tile[32][33];
  const int tx = threadIdx.x & 31, ty = threadIdx.x >> 5;
  const int t0 = blockIdx.x * 32;   // T/32 = 8
  const int i0 = blockIdx.y * 32;   // I/32 = 32
  const int b  = blockIdx.z;        // 128
  const size_t I = 1024, T = 256;
#pragma unroll
  for (int r = 0; r < 4; ++r)
    tile[ty + r * 8][tx] = sp[((size_t)b * I + i0 + ty + r * 8) * T + t0 + tx];
  __syncthreads();
#pragma unroll
  for (int r = 0; r < 4; ++r)
    S[((size_t)(t0 + ty + r * 8) * 128 + b) * I + i0 + tx] = f2bf(tile[tx][ty + r * 8]);
}

// ---------- bf16 MFMA GEMM: C = A * Bt^T. A (M=32768 x K), Bt (N x K), C (M x N), all bf16.
// 128x128 tile, BK=64, 4 waves (2x2), 16x16x32 MFMA.
// Coalesced staging: each gload16 stages 8 rows x 128B (lane l -> row l>>3, chunk l&7),
// per-instruction global footprint = 8 fully-used 128B segments.
// T2 XOR swizzle (G4): LDS [128][64] row-major, physical chunk p of row r holds logical
// chunk p^(r&7). Staging pre-swizzles the GLOBAL source (c = (l&7)^(l>>3), LDS dest
// linear); reads swizzle the chunk index -> ds_read_b128 conflict-free.
// XCD chunked swizzle (bijective: nwg%8==0): all nt-blocks of one mt-panel on one XCD.
// Activity gating: row-panel mt == timestep t; clear flag bit -> skip (consumer uses c=0).
__global__ __launch_bounds__(256) void gemm_bf16(const u16* __restrict__ A,
                                                 const u16* __restrict__ Bt,
                                                 u16* __restrict__ C,
                                                 int K, int N,
                                                 const u32* __restrict__ flags) {
  __shared__ __align__(16) u16 As[128][64];
  __shared__ __align__(16) u16 Bs[128][64];
  const int tid  = threadIdx.x;
  const int lane = tid & 63;
  const int wave = tid >> 6;
  const int nTn  = N >> 7;
  // XCD chunked swizzle over nwg = 256*nTn blocks (divisible by 8)
  const int chunk = (256 * nTn) >> 3;
  const int swz   = ((int)blockIdx.x & 7) * chunk + ((int)blockIdx.x >> 3);
  const int mt    = swz / nTn;
  const int nt    = swz - mt * nTn;

  if (flags && (((flags[mt >> 5] >> (mt & 31)) & 1u) == 0u)) return;

  floatx4 acc[4][4];
#pragma unroll
  for (int i = 0; i < 4; ++i)
#pragma unroll
    for (int j = 0; j < 4; ++j)
      acc[i][j] = (floatx4){0.f, 0.f, 0.f, 0.f};

  const int wm = (wave >> 1) * 64;
  const int wn = (wave & 1) * 64;
  const int fr = lane & 15;   // fragment row within 16
  const int fg = lane >> 4;   // fragment k-group (0..3)

  // staging geometry: lane l covers row r_l = l>>3, physical chunk p_l = l&7;
  // global logical chunk c_l = p_l ^ r_l (pre-swizzled source).
  const int r_l = lane >> 3;
  const int c_l = (lane & 7) ^ r_l;

  const u16* gA = A  + (size_t)(mt * 128) * K;
  const u16* gB = Bt + (size_t)(nt * 128) * K;

  for (int kt = 0; kt < K; kt += 64) {
#pragma unroll
    for (int q = 0; q < 4; ++q) {
      const int rb0 = (wave * 4 + q) * 8;          // multiple of 8
      const int rt  = rb0 + r_l;
      gload16(gA + (size_t)rt * K + kt + c_l * 8, &As[rb0][0]);
      gload16(gB + (size_t)rt * K + kt + c_l * 8, &Bs[rb0][0]);
    }
    __syncthreads();   // drains vmcnt; LDS tiles ready

#pragma unroll
    for (int kk = 0; kk < 2; ++kk) {
      bhalf8 af[4], bf[4];
#pragma unroll
      for (int i = 0; i < 4; ++i) {
        const int ra = wm + i * 16 + fr;
        const int rb = wn + i * 16 + fr;
        af[i] = *(const bhalf8*)(&As[ra][((((kk << 2) | fg) ^ (ra & 7)) << 3)]);
        bf[i] = *(const bhalf8*)(&Bs[rb][((((kk << 2) | fg) ^ (rb & 7)) << 3)]);
      }
#pragma unroll
      for (int i = 0; i < 4; ++i)
#pragma unroll
        for (int j = 0; j < 4; ++j)
          acc[i][j] = __builtin_amdgcn_mfma_f32_16x16x32_bf16(af[i], bf[j], acc[i][j], 0, 0, 0);
    }
    __syncthreads();   // protect LDS before next stage
  }

  // C/D layout: col = lane&15, row = (lane>>4)*4 + reg
  const size_t rbase = (size_t)(mt * 128 + wm + fg * 4);
  const size_t cbase = (size_t)(nt * 128 + wn + fr);
#pragma unroll
  for (int i = 0; i < 4; ++i)
#pragma unroll
    for (int j = 0; j < 4; ++j)
#pragma unroll
      for (int r = 0; r < 4; ++r)
        C[(rbase + i * 16 + r) * (size_t)N + cbase + j * 16] = f2bf(acc[i][j][r]);
}

// ---------- LIF scan over T for one layer ----------
// Fast path: all-zero aflag -> layer provably silent (v stays -65): zero outputs,
// skip sshift entirely (next GEMM is flag-skipped and never reads it).
__global__ __launch_bounds__(256) void lif_scan(const u16* __restrict__ Cur,
                                                const u32* __restrict__ aflag,
                                                float* __restrict__ out,
                                                u16* __restrict__ sshift,
                                                u32* __restrict__ oflag,
                                                float* __restrict__ rates,
                                                int H) {
  const int gidx = blockIdx.x * 256 + threadIdx.x;  // = b*H + h
  const size_t BH = (size_t)128 * H;
  u32 fw[8];
  u32 any = 0;
#pragma unroll
  for (int w = 0; w < 8; ++w) {
    fw[w] = aflag ? aflag[w] : 0xffffffffu;
    any |= fw[w];
  }

  if (any == 0u) {   // block-uniform: silent layer
    const float4 z = {0.f, 0.f, 0.f, 0.f};
    float* o = out + (size_t)gidx * 256;
#pragma unroll
    for (int q = 0; q < 64; ++q) *(float4*)(o + q * 4) = z;
    if (rates) rates[gidx] = 0.f;
    return;
  }

  float v = -65.f;
  float ssum = 0.f;
  if (sshift) sshift[gidx] = 0;  // t=0 slice: s_init = 0
  float buf[16];
  for (int t0 = 0; t0 < 256; t0 += 16) {
    u32 wavemask = 0;
#pragma unroll
    for (int j = 0; j < 16; ++j) {
      const int t = t0 + j;
      const bool act = ((fw[t >> 5] >> (t & 31)) & 1u) != 0u;
      const float c  = act ? bf2f(Cur[(size_t)t * BH + gidx]) : 0.f;
      const float vn = v + 0.05f * ((-65.f - v) + c);   // v + (DT/TAU)*((V_REST - v) + cur)
      const float s  = (vn >= -50.f) ? 1.f : 0.f;       // spike(v_new - V_TH)
      v = vn - s * (vn + 65.f);                         // soft reset
      ssum += s;
      buf[j] = s;
      if (sshift && t < 255)
        sshift[(size_t)(t + 1) * BH + gidx] = (u16)((s != 0.f) ? 0x3F80u : 0u);
      if (oflag) {
        if (__ballot(s != 0.f) != 0ull) wavemask |= (1u << j);
      }
    }
    if (t0 == 240) wavemask &= 0x7fffu;   // t=255 spikes have no next step
    if (oflag && wavemask && ((threadIdx.x & 63) == 0)) {
      const unsigned long long m = (unsigned long long)wavemask << ((t0 + 1) & 31);
      const int w = (t0 + 1) >> 5;
      if ((u32)m) atomicOr(&oflag[w], (u32)m);
      if (m >> 32) atomicOr(&oflag[w + 1], (u32)(m >> 32));
    }
    float* o = out + (size_t)gidx * 256 + t0;
#pragma unroll
    for (int q = 0; q < 4; ++q) {
      float4 wv;
      wv.x = buf[q * 4 + 0]; wv.y = buf[q * 4 + 1];
      wv.z = buf[q * 4 + 2]; wv.w = buf[q * 4 + 3];
      *(float4*)(o + q * 4) = wv;
    }
  }
  if (rates) rates[gidx] = ssum * (1.f / 256.f);
}

// ---------- launch ----------
extern "C" void kernel_launch(void* const* d_in, const int* in_sizes, int n_in,
                              void* d_out, int out_size, void* d_ws, size_t ws_size,
                              hipStream_t stream) {
  const float* w0 = (const float*)d_in[0];  // 1024x1024
  const float* w1 = (const float*)d_in[1];  // 1024x1024
  const float* w2 = (const float*)d_in[2];  // 1024x512
  const float* w3 = (const float*)d_in[3];  // 512x256
  const float* w4 = (const float*)d_in[4];  // 256x128
  const float* spikes = (const float*)d_in[5];  // (128, 1024, 256)

  uint8_t* ws = (uint8_t*)d_ws;
  u16* S0 = (u16*)(ws + 0);            // 64 MiB (input spikes^T / shift ping)
  u16* S1 = (u16*)(ws + 67108864);     // 64 MiB (shift pong)
  u16* Cb = (u16*)(ws + 134217728);    // 64 MiB (bf16 current, reused per layer)
  u16* W0 = (u16*)(ws + 201326592);    // 2 MiB
  u16* W1 = (u16*)(ws + 203423744);    // 2 MiB
  u16* W2 = (u16*)(ws + 205520896);    // 1 MiB
  u16* W3 = (u16*)(ws + 206569472);    // 256 KiB
  u16* W4 = (u16*)(ws + 206831616);    // 64 KiB
  u32* FL = (u32*)(ws + 206897152);    // 64 u32: 4 layers x 16
  u32* F1 = FL +  0;
  u32* F2 = FL + 16;
  u32* F3 = FL + 32;
  u32* F4 = FL + 48;

  float* out0  = (float*)d_out;            // (128,1024,256)
  float* out1  = out0 + 33554432;          // (128,1024,256)
  float* out2  = out0 + 67108864;          // (128, 512,256)
  float* out3  = out0 + 83886080;          // (128, 256,256)
  float* out4  = out0 + 92274688;          // (128, 128,256)
  float* rates = out0 + 96468992;          // (128,128)

  // 1) fused weight prep (5 transposes + flag zeroing)
  prep_weights<<<2721, 256, 0, stream>>>(w0, w1, w2, w3, w4, W0, W1, W2, W3, W4, FL);

  // 2) input spikes -> (T*B, 1024) bf16
  spike_transpose<<<dim3(8, 32, 128), 256, 0, stream>>>(spikes, S0);

  // 3) layer pipeline: gemm -> lif, activity-gated per timestep panel
  gemm_bf16<<<256 * 8, 256, 0, stream>>>(S0, W0, Cb, 1024, 1024, nullptr);
  lif_scan<<<512, 256, 0, stream>>>(Cb, nullptr, out0, S1, F1, nullptr, 1024);

  gemm_bf16<<<256 * 8, 256, 0, stream>>>(S1, W1, Cb, 1024, 1024, F1);
  lif_scan<<<512, 256, 0, stream>>>(Cb, F1, out1, S0, F2, nullptr, 1024);

  gemm_bf16<<<256 * 4, 256, 0, stream>>>(S0, W2, Cb, 1024, 512, F2);
  lif_scan<<<256, 256, 0, stream>>>(Cb, F2, out2, S1, F3, nullptr, 512);

  gemm_bf16<<<256 * 2, 256, 0, stream>>>(S1, W3, Cb, 512, 256, F3);
  lif_scan<<<128, 256, 0, stream>>>(Cb, F3, out3, S0, F4, nullptr, 256);

  gemm_bf16<<<256 * 1, 256, 0, stream>>>(S0, W4, Cb, 256, 128, F4);
  lif_scan<<<64, 256, 0, stream>>>(Cb, F4, out4, nullptr, nullptr, rates, 128);
}

// Round 13
// 752.396 us; speedup vs baseline: 1.9056x; 1.0506x over previous
//
#include <hip/hip_runtime.h>
#include <cstdint>

using u16 = unsigned short;
using u32 = unsigned int;
typedef __attribute__((ext_vector_type(8))) short bhalf8;
typedef __attribute__((ext_vector_type(4))) float floatx4;

// ---------- bf16 helpers (storage = ushort, round-to-nearest-even) ----------
__device__ __forceinline__ float bf2f(u16 u) {
  union { unsigned int i; float f; } v; v.i = ((unsigned int)u) << 16; return v.f;
}
__device__ __forceinline__ u16 f2bf(float f) {
  union { float f; unsigned int i; } v; v.f = f;
  unsigned int r = v.i + 0x7fffu + ((v.i >> 16) & 1u);
  return (u16)(r >> 16);
}

__device__ __forceinline__ void gload16(const void* g, void* l) {
  __builtin_amdgcn_global_load_lds((const __attribute__((address_space(1))) void*)g,
                                   (__attribute__((address_space(3))) void*)l, 16, 0, 0);
}

// ---------- fused prep: 5x weight (transpose+relu+bf16) + flag zero + spike transpose ----------
// bid < 2720: weight 32x32 tiles | bid == 2720: flags | bid > 2720: spike transpose
// (32768 blocks: rel -> b = rel>>8, i0 = ((rel>>3)&31)*32, t0 = (rel&7)*32).
__global__ __launch_bounds__(256) void prep_all(
    const float* __restrict__ w0, const float* __restrict__ w1,
    const float* __restrict__ w2, const float* __restrict__ w3,
    const float* __restrict__ w4, const float* __restrict__ sp,
    u16* __restrict__ W0, u16* __restrict__ W1, u16* __restrict__ W2,
    u16* __restrict__ W3, u16* __restrict__ W4, u16* __restrict__ S,
    u32* __restrict__ flags) {
  const int bid = blockIdx.x;
  const int tid = threadIdx.x;
  const int tx = tid & 31, ty = tid >> 5;
  __shared__ float tile[32][33];

  if (bid == 2720) {
    if (tid < 64) flags[tid] = 0u;   // 4 layers x 16 words
    return;
  }
  if (bid > 2720) {                  // spike transpose (B=128, I=1024, T=256) -> (T*B, I) bf16
    const int rel = bid - 2721;
    const int b  = rel >> 8;
    const int i0 = ((rel >> 3) & 31) * 32;
    const int t0 = (rel & 7) * 32;
    const size_t I = 1024, T = 256;
#pragma unroll
    for (int r = 0; r < 4; ++r)
      tile[ty + r * 8][tx] = sp[((size_t)b * I + i0 + ty + r * 8) * T + t0 + tx];
    __syncthreads();
#pragma unroll
    for (int r = 0; r < 4; ++r)
      S[((size_t)(t0 + ty + r * 8) * 128 + b) * I + i0 + tx] = f2bf(tile[tx][ty + r * 8]);
    return;
  }

  // weight transpose segments
  const float* W; u16* Wt; int K, N, rel;
  if (bid < 1024)      { W = w0; Wt = W0; K = 1024; N = 1024; rel = bid; }
  else if (bid < 2048) { W = w1; Wt = W1; K = 1024; N = 1024; rel = bid - 1024; }
  else if (bid < 2560) { W = w2; Wt = W2; K = 1024; N =  512; rel = bid - 2048; }
  else if (bid < 2688) { W = w3; Wt = W3; K =  512; N =  256; rel = bid - 2560; }
  else                 { W = w4; Wt = W4; K =  256; N =  128; rel = bid - 2688; }
  const int nx = K >> 5;
  const int k0 = (rel % nx) * 32;
  const int n0 = (rel / nx) * 32;
#pragma unroll
  for (int r = 0; r < 4; ++r)
    tile[ty + r * 8][tx] = W[(size_t)(k0 + ty + r * 8) * N + n0 + tx];
  __syncthreads();
#pragma unroll
  for (int r = 0; r < 4; ++r)
    Wt[(size_t)(n0 + ty + r * 8) * K + k0 + tx] = f2bf(fmaxf(tile[tx][ty + r * 8], 0.f));
}

// ---------- bf16 MFMA GEMM: C = A * Bt^T. A (M=32768 x K), Bt (N x K), C (M x N), all bf16.
// 128x128 tile, BK=64, 4 waves (2x2), 16x16x32 MFMA. Coalesced gload16 staging
// (lane l -> row l>>3, chunk l&7; 8 fully-used 128B segments per instruction).
// T2 XOR swizzle via pre-swizzled global source (c = (l&7)^(l>>3)), swizzled read.
// XCD chunked swizzle (bijective; nwg%8==0). Activity gating: panel mt == timestep t.
__global__ __launch_bounds__(256) void gemm_bf16(const u16* __restrict__ A,
                                                 const u16* __restrict__ Bt,
                                                 u16* __restrict__ C,
                                                 int K, int N,
                                                 const u32* __restrict__ flags) {
  __shared__ __align__(16) u16 As[128][64];
  __shared__ __align__(16) u16 Bs[128][64];
  const int tid  = threadIdx.x;
  const int lane = tid & 63;
  const int wave = tid >> 6;
  const int nTn  = N >> 7;
  const int chunk = (256 * nTn) >> 3;
  const int swz   = ((int)blockIdx.x & 7) * chunk + ((int)blockIdx.x >> 3);
  const int mt    = swz / nTn;
  const int nt    = swz - mt * nTn;

  if (flags && (((flags[mt >> 5] >> (mt & 31)) & 1u) == 0u)) return;

  floatx4 acc[4][4];
#pragma unroll
  for (int i = 0; i < 4; ++i)
#pragma unroll
    for (int j = 0; j < 4; ++j)
      acc[i][j] = (floatx4){0.f, 0.f, 0.f, 0.f};

  const int wm = (wave >> 1) * 64;
  const int wn = (wave & 1) * 64;
  const int fr = lane & 15;
  const int fg = lane >> 4;

  const int r_l = lane >> 3;
  const int c_l = (lane & 7) ^ r_l;

  const u16* gA = A  + (size_t)(mt * 128) * K;
  const u16* gB = Bt + (size_t)(nt * 128) * K;

  for (int kt = 0; kt < K; kt += 64) {
#pragma unroll
    for (int q = 0; q < 4; ++q) {
      const int rb0 = (wave * 4 + q) * 8;
      const int rt  = rb0 + r_l;
      gload16(gA + (size_t)rt * K + kt + c_l * 8, &As[rb0][0]);
      gload16(gB + (size_t)rt * K + kt + c_l * 8, &Bs[rb0][0]);
    }
    __syncthreads();

#pragma unroll
    for (int kk = 0; kk < 2; ++kk) {
      bhalf8 af[4], bf[4];
#pragma unroll
      for (int i = 0; i < 4; ++i) {
        const int ra = wm + i * 16 + fr;
        const int rb = wn + i * 16 + fr;
        af[i] = *(const bhalf8*)(&As[ra][((((kk << 2) | fg) ^ (ra & 7)) << 3)]);
        bf[i] = *(const bhalf8*)(&Bs[rb][((((kk << 2) | fg) ^ (rb & 7)) << 3)]);
      }
#pragma unroll
      for (int i = 0; i < 4; ++i)
#pragma unroll
        for (int j = 0; j < 4; ++j)
          acc[i][j] = __builtin_amdgcn_mfma_f32_16x16x32_bf16(af[i], bf[j], acc[i][j], 0, 0, 0);
    }
    __syncthreads();
  }

  const size_t rbase = (size_t)(mt * 128 + wm + fg * 4);
  const size_t cbase = (size_t)(nt * 128 + wn + fr);
#pragma unroll
  for (int i = 0; i < 4; ++i)
#pragma unroll
    for (int j = 0; j < 4; ++j)
#pragma unroll
      for (int r = 0; r < 4; ++r)
        C[(rbase + i * 16 + r) * (size_t)N + cbase + j * 16] = f2bf(acc[i][j][r]);
}

// ---------- LIF scan over T for one layer ----------
// Fast path (all-zero aflag): layer provably silent -> BLOCK-CONTIGUOUS zero fill
// (each block fills 256KB linearly; wave writes 1KB/instruction, full 128B lines),
// skip sshift entirely (next GEMM is flag-skipped and never reads it).
__global__ __launch_bounds__(256) void lif_scan(const u16* __restrict__ Cur,
                                                const u32* __restrict__ aflag,
                                                float* __restrict__ out,
                                                u16* __restrict__ sshift,
                                                u32* __restrict__ oflag,
                                                float* __restrict__ rates,
                                                int H) {
  const int gidx = blockIdx.x * 256 + threadIdx.x;  // = b*H + h
  const size_t BH = (size_t)128 * H;
  u32 fw[8];
  u32 any = 0;
#pragma unroll
  for (int w = 0; w < 8; ++w) {
    fw[w] = aflag ? aflag[w] : 0xffffffffu;
    any |= fw[w];
  }

  if (any == 0u) {   // block-uniform: silent layer -> linear fill
    const float4 z = {0.f, 0.f, 0.f, 0.f};
    float* base = out + (size_t)blockIdx.x * 65536 + threadIdx.x * 4;
#pragma unroll
    for (int k = 0; k < 64; ++k)
      *(float4*)(base + (size_t)k * 1024) = z;
    if (rates) rates[gidx] = 0.f;
    return;
  }

  float v = -65.f;
  float ssum = 0.f;
  if (sshift) sshift[gidx] = 0;  // t=0 slice: s_init = 0
  float buf[16];
  for (int t0 = 0; t0 < 256; t0 += 16) {
    u32 wavemask = 0;
#pragma unroll
    for (int j = 0; j < 16; ++j) {
      const int t = t0 + j;
      const bool act = ((fw[t >> 5] >> (t & 31)) & 1u) != 0u;
      const float c  = act ? bf2f(Cur[(size_t)t * BH + gidx]) : 0.f;
      const float vn = v + 0.05f * ((-65.f - v) + c);   // v + (DT/TAU)*((V_REST - v) + cur)
      const float s  = (vn >= -50.f) ? 1.f : 0.f;       // spike(v_new - V_TH)
      v = vn - s * (vn + 65.f);                         // soft reset
      ssum += s;
      buf[j] = s;
      if (sshift && t < 255)
        sshift[(size_t)(t + 1) * BH + gidx] = (u16)((s != 0.f) ? 0x3F80u : 0u);
      if (oflag) {
        if (__ballot(s != 0.f) != 0ull) wavemask |= (1u << j);
      }
    }
    if (t0 == 240) wavemask &= 0x7fffu;   // t=255 spikes have no next step
    if (oflag && wavemask && ((threadIdx.x & 63) == 0)) {
      const unsigned long long m = (unsigned long long)wavemask << ((t0 + 1) & 31);
      const int w = (t0 + 1) >> 5;
      if ((u32)m) atomicOr(&oflag[w], (u32)m);
      if (m >> 32) atomicOr(&oflag[w + 1], (u32)(m >> 32));
    }
    float* o = out + (size_t)gidx * 256 + t0;
#pragma unroll
    for (int q = 0; q < 4; ++q) {
      float4 wv;
      wv.x = buf[q * 4 + 0]; wv.y = buf[q * 4 + 1];
      wv.z = buf[q * 4 + 2]; wv.w = buf[q * 4 + 3];
      *(float4*)(o + q * 4) = wv;
    }
  }
  if (rates) rates[gidx] = ssum * (1.f / 256.f);
}

// ---------- launch ----------
extern "C" void kernel_launch(void* const* d_in, const int* in_sizes, int n_in,
                              void* d_out, int out_size, void* d_ws, size_t ws_size,
                              hipStream_t stream) {
  const float* w0 = (const float*)d_in[0];  // 1024x1024
  const float* w1 = (const float*)d_in[1];  // 1024x1024
  const float* w2 = (const float*)d_in[2];  // 1024x512
  const float* w3 = (const float*)d_in[3];  // 512x256
  const float* w4 = (const float*)d_in[4];  // 256x128
  const float* spikes = (const float*)d_in[5];  // (128, 1024, 256)

  uint8_t* ws = (uint8_t*)d_ws;
  u16* S0 = (u16*)(ws + 0);            // 64 MiB (input spikes^T / shift ping)
  u16* S1 = (u16*)(ws + 67108864);     // 64 MiB (shift pong)
  u16* Cb = (u16*)(ws + 134217728);    // 64 MiB (bf16 current, reused per layer)
  u16* W0 = (u16*)(ws + 201326592);    // 2 MiB
  u16* W1 = (u16*)(ws + 203423744);    // 2 MiB
  u16* W2 = (u16*)(ws + 205520896);    // 1 MiB
  u16* W3 = (u16*)(ws + 206569472);    // 256 KiB
  u16* W4 = (u16*)(ws + 206831616);    // 64 KiB
  u32* FL = (u32*)(ws + 206897152);    // 64 u32: 4 layers x 16
  u32* F1 = FL +  0;
  u32* F2 = FL + 16;
  u32* F3 = FL + 32;
  u32* F4 = FL + 48;

  float* out0  = (float*)d_out;            // (128,1024,256)
  float* out1  = out0 + 33554432;          // (128,1024,256)
  float* out2  = out0 + 67108864;          // (128, 512,256)
  float* out3  = out0 + 83886080;          // (128, 256,256)
  float* out4  = out0 + 92274688;          // (128, 128,256)
  float* rates = out0 + 96468992;          // (128,128)

  // 1) fused prep: 5 weight transposes + flag zero + input spike transpose
  prep_all<<<2721 + 32768, 256, 0, stream>>>(w0, w1, w2, w3, w4, spikes,
                                             W0, W1, W2, W3, W4, S0, FL);

  // 2) layer pipeline: gemm -> lif, activity-gated per timestep panel
  gemm_bf16<<<256 * 8, 256, 0, stream>>>(S0, W0, Cb, 1024, 1024, nullptr);
  lif_scan<<<512, 256, 0, stream>>>(Cb, nullptr, out0, S1, F1, nullptr, 1024);

  gemm_bf16<<<256 * 8, 256, 0, stream>>>(S1, W1, Cb, 1024, 1024, F1);
  lif_scan<<<512, 256, 0, stream>>>(Cb, F1, out1, S0, F2, nullptr, 1024);

  gemm_bf16<<<256 * 4, 256, 0, stream>>>(S0, W2, Cb, 1024, 512, F2);
  lif_scan<<<256, 256, 0, stream>>>(Cb, F2, out2, S1, F3, nullptr, 512);

  gemm_bf16<<<256 * 2, 256, 0, stream>>>(S1, W3, Cb, 512, 256, F3);
  lif_scan<<<128, 256, 0, stream>>>(Cb, F3, out3, S0, F4, nullptr, 256);

  gemm_bf16<<<256 * 1, 256, 0, stream>>>(S0, W4, Cb, 256, 128, F4);
  lif_scan<<<64, 256, 0, stream>>>(Cb, F4, out4, nullptr, nullptr, rates, 128);
}

// Round 15
// 684.698 us; speedup vs baseline: 2.0940x; 1.0989x over previous
//
#include <hip/hip_runtime.h>
#include <cstdint>

using u16 = unsigned short;
using u32 = unsigned int;
typedef __attribute__((ext_vector_type(8))) short bhalf8;
typedef __attribute__((ext_vector_type(4))) float floatx4;

// ---------- bf16 helpers (storage = ushort, round-to-nearest-even) ----------
__device__ __forceinline__ float bf2f(u16 u) {
  union { unsigned int i; float f; } v; v.i = ((unsigned int)u) << 16; return v.f;
}
__device__ __forceinline__ u16 f2bf(float f) {
  union { float f; unsigned int i; } v; v.f = f;
  unsigned int r = v.i + 0x7fffu + ((v.i >> 16) & 1u);
  return (u16)(r >> 16);
}

__device__ __forceinline__ void gload16(const void* g, void* l) {
  __builtin_amdgcn_global_load_lds((const __attribute__((address_space(1))) void*)g,
                                   (__attribute__((address_space(3))) void*)l, 16, 0, 0);
}

// ---------- fused prep: 5x weight (transpose+relu+bf16) + flag zero + spike transpose ----------
// bid < 2720: weight 32x32 tiles | bid == 2720: flags | bid > 2720: spike transpose
// Spike transpose vectorized: float4 loads (t-contig), ushort4 stores (i-contig).
__global__ __launch_bounds__(256) void prep_all(
    const float* __restrict__ w0, const float* __restrict__ w1,
    const float* __restrict__ w2, const float* __restrict__ w3,
    const float* __restrict__ w4, const float* __restrict__ sp,
    u16* __restrict__ W0, u16* __restrict__ W1, u16* __restrict__ W2,
    u16* __restrict__ W3, u16* __restrict__ W4, u16* __restrict__ S,
    u32* __restrict__ flags) {
  const int bid = blockIdx.x;
  const int tid = threadIdx.x;
  __shared__ float tile[32][33];

  if (bid == 2720) {
    if (tid < 64) flags[tid] = 0u;   // 4 layers x 16 words
    return;
  }
  if (bid > 2720) {                  // spike transpose (B=128, I=1024, T=256) -> (T*B, I) bf16
    const int rel = bid - 2721;
    const int b  = rel >> 8;
    const int i0 = ((rel >> 3) & 31) * 32;
    const int t0 = (rel & 7) * 32;
    const size_t I = 1024, T = 256;
    // load: thread (r = tid>>3, c4 = (tid&7)*4) -> float4 along t
    {
      const int r  = tid >> 3;
      const int c4 = (tid & 7) * 4;
      const float4 v = *(const float4*)(sp + ((size_t)b * I + i0 + r) * T + t0 + c4);
      tile[r][c4 + 0] = v.x; tile[r][c4 + 1] = v.y;
      tile[r][c4 + 2] = v.z; tile[r][c4 + 3] = v.w;
    }
    __syncthreads();
    // store: thread (tr = tid>>3, ic = tid&7) -> ushort4 along i
    {
      const int tr = tid >> 3;
      const int ic = (tid & 7) * 4;
      ushort4 o;
      o.x = f2bf(tile[ic + 0][tr]);
      o.y = f2bf(tile[ic + 1][tr]);
      o.z = f2bf(tile[ic + 2][tr]);
      o.w = f2bf(tile[ic + 3][tr]);
      *(ushort4*)(&S[((size_t)(t0 + tr) * 128 + b) * I + i0 + ic]) = o;
    }
    return;
  }

  // weight transpose segments
  const int tx = tid & 31, ty = tid >> 5;
  const float* W; u16* Wt; int K, N, rel;
  if (bid < 1024)      { W = w0; Wt = W0; K = 1024; N = 1024; rel = bid; }
  else if (bid < 2048) { W = w1; Wt = W1; K = 1024; N = 1024; rel = bid - 1024; }
  else if (bid < 2560) { W = w2; Wt = W2; K = 1024; N =  512; rel = bid - 2048; }
  else if (bid < 2688) { W = w3; Wt = W3; K =  512; N =  256; rel = bid - 2560; }
  else                 { W = w4; Wt = W4; K =  256; N =  128; rel = bid - 2688; }
  const int nx = K >> 5;
  const int k0 = (rel % nx) * 32;
  const int n0 = (rel / nx) * 32;
#pragma unroll
  for (int r = 0; r < 4; ++r)
    tile[ty + r * 8][tx] = W[(size_t)(k0 + ty + r * 8) * N + n0 + tx];
  __syncthreads();
#pragma unroll
  for (int r = 0; r < 4; ++r)
    Wt[(size_t)(n0 + ty + r * 8) * K + k0 + tx] = f2bf(fmaxf(tile[tx][ty + r * 8], 0.f));
}

// ---------- bf16 MFMA GEMM (unchanged from R12/R13) ----------
__global__ __launch_bounds__(256) void gemm_bf16(const u16* __restrict__ A,
                                                 const u16* __restrict__ Bt,
                                                 u16* __restrict__ C,
                                                 int K, int N,
                                                 const u32* __restrict__ flags) {
  __shared__ __align__(16) u16 As[128][64];
  __shared__ __align__(16) u16 Bs[128][64];
  const int tid  = threadIdx.x;
  const int lane = tid & 63;
  const int wave = tid >> 6;
  const int nTn  = N >> 7;
  const int chunk = (256 * nTn) >> 3;
  const int swz   = ((int)blockIdx.x & 7) * chunk + ((int)blockIdx.x >> 3);
  const int mt    = swz / nTn;
  const int nt    = swz - mt * nTn;

  if (flags && (((flags[mt >> 5] >> (mt & 31)) & 1u) == 0u)) return;

  floatx4 acc[4][4];
#pragma unroll
  for (int i = 0; i < 4; ++i)
#pragma unroll
    for (int j = 0; j < 4; ++j)
      acc[i][j] = (floatx4){0.f, 0.f, 0.f, 0.f};

  const int wm = (wave >> 1) * 64;
  const int wn = (wave & 1) * 64;
  const int fr = lane & 15;
  const int fg = lane >> 4;

  const int r_l = lane >> 3;
  const int c_l = (lane & 7) ^ r_l;

  const u16* gA = A  + (size_t)(mt * 128) * K;
  const u16* gB = Bt + (size_t)(nt * 128) * K;

  for (int kt = 0; kt < K; kt += 64) {
#pragma unroll
    for (int q = 0; q < 4; ++q) {
      const int rb0 = (wave * 4 + q) * 8;
      const int rt  = rb0 + r_l;
      gload16(gA + (size_t)rt * K + kt + c_l * 8, &As[rb0][0]);
      gload16(gB + (size_t)rt * K + kt + c_l * 8, &Bs[rb0][0]);
    }
    __syncthreads();

#pragma unroll
    for (int kk = 0; kk < 2; ++kk) {
      bhalf8 af[4], bf[4];
#pragma unroll
      for (int i = 0; i < 4; ++i) {
        const int ra = wm + i * 16 + fr;
        const int rb = wn + i * 16 + fr;
        af[i] = *(const bhalf8*)(&As[ra][((((kk << 2) | fg) ^ (ra & 7)) << 3)]);
        bf[i] = *(const bhalf8*)(&Bs[rb][((((kk << 2) | fg) ^ (rb & 7)) << 3)]);
      }
#pragma unroll
      for (int i = 0; i < 4; ++i)
#pragma unroll
        for (int j = 0; j < 4; ++j)
          acc[i][j] = __builtin_amdgcn_mfma_f32_16x16x32_bf16(af[i], bf[j], acc[i][j], 0, 0, 0);
    }
    __syncthreads();
  }

  const size_t rbase = (size_t)(mt * 128 + wm + fg * 4);
  const size_t cbase = (size_t)(nt * 128 + wn + fr);
#pragma unroll
  for (int i = 0; i < 4; ++i)
#pragma unroll
    for (int j = 0; j < 4; ++j)
#pragma unroll
      for (int r = 0; r < 4; ++r)
        C[(rbase + i * 16 + r) * (size_t)N + cbase + j * 16] = f2bf(acc[i][j][r]);
}

// ---------- LIF scan over T for one layer ----------
// Active path: bit-packed spikes (8x u32/thread), post-scan LDS phase emits
// full-128B-line out stores (8 rows/instruction). Rates via popcount.
// Fast path (all-zero aflag): linear block-contiguous zero fill, skip sshift.
__global__ __launch_bounds__(256) void lif_scan(const u16* __restrict__ Cur,
                                                const u32* __restrict__ aflag,
                                                float* __restrict__ out,
                                                u16* __restrict__ sshift,
                                                u32* __restrict__ oflag,
                                                float* __restrict__ rates,
                                                int H) {
  const int tid  = threadIdx.x;
  const int gidx = blockIdx.x * 256 + tid;  // = b*H + h
  const size_t BH = (size_t)128 * H;
  u32 fw[8];
  u32 any = 0;
#pragma unroll
  for (int w = 0; w < 8; ++w) {
    fw[w] = aflag ? aflag[w] : 0xffffffffu;
    any |= fw[w];
  }

  if (any == 0u) {   // block-uniform: silent layer -> linear fill (256KB/block)
    const float4 z = {0.f, 0.f, 0.f, 0.f};
    float* base = out + (size_t)blockIdx.x * 65536 + tid * 4;
    for (int k = 0; k < 64; ++k)
      *(float4*)(base + (size_t)k * 1024) = z;
    if (rates) rates[gidx] = 0.f;
    return;
  }

  float v = -65.f;
  u32 spk[8];
  if (sshift) sshift[gidx] = 0;  // t=0 slice: s_init = 0
#pragma unroll
  for (int t0c = 0; t0c < 8; ++t0c) {
    const int t0 = t0c * 32;
    u32 word = 0, cmask = 0;
#pragma unroll
    for (int j = 0; j < 32; ++j) {
      const int t = t0 + j;
      const bool act = ((fw[t >> 5] >> (t & 31)) & 1u) != 0u;
      const float cc = act ? bf2f(Cur[(size_t)t * BH + gidx]) : 0.f;
      const float vn = v + 0.05f * ((-65.f - v) + cc);  // v + (DT/TAU)*((V_REST-v)+cur)
      const u32 sb = (vn >= -50.f) ? 1u : 0u;           // spike(v_new - V_TH)
      v = sb ? -65.f : vn;                              // soft reset (exact)
      word |= sb << j;
      if (sshift && t < 255)
        sshift[(size_t)(t + 1) * BH + gidx] = (u16)(sb ? 0x3F80u : 0u);
      if (oflag) {
        if (__ballot(sb != 0u) != 0ull) cmask |= (1u << j);
      }
    }
    spk[t0c] = word;
    if (oflag) {
      const u32 cm = (t0c == 7) ? (cmask & 0x7fffffffu) : cmask;  // t=255: no next step
      if (cm && ((tid & 63) == 0)) {
        // spikes at t -> flag bits t+1: window [t0..t0+63], m = cm<<1
        const unsigned long long m = (unsigned long long)cm << 1;
        atomicOr(&oflag[t0c], (u32)m);
        if ((u32)(m >> 32)) atomicOr(&oflag[t0c + 1], (u32)(m >> 32));
      }
    }
  }
  if (rates) {
    int cnt = 0;
#pragma unroll
    for (int c = 0; c < 8; ++c) cnt += __popc(spk[c]);
    rates[gidx] = (float)cnt * (1.f / 256.f);
  }

  // out writes: deposit bitmasks to LDS (stride 9: conflict-free), then each
  // wave emits full 128B lines (8 rows x one 32-step chunk per instruction).
  __shared__ u32 lds[256 * 9];
#pragma unroll
  for (int c = 0; c < 8; ++c) lds[tid * 9 + c] = spk[c];
  __syncthreads();
  const int wv  = tid >> 6, ln = tid & 63;
  const int grp = ln >> 3;        // row subgroup (8 rows/instr)
  const int sub = ln & 7;         // 4 t-steps per lane
  float* ob = out + (size_t)blockIdx.x * 65536;
  for (int rr = 0; rr < 64; rr += 8) {
    const int row = wv * 64 + rr + grp;
#pragma unroll
    for (int c = 0; c < 8; ++c) {
      const u32 wb = lds[row * 9 + c] >> (sub * 4);
      float4 f;
      f.x = (float)(wb & 1u); f.y = (float)((wb >> 1) & 1u);
      f.z = (float)((wb >> 2) & 1u); f.w = (float)((wb >> 3) & 1u);
      *(float4*)(ob + (size_t)row * 256 + c * 32 + sub * 4) = f;
    }
  }
}

// ---------- launch ----------
extern "C" void kernel_launch(void* const* d_in, const int* in_sizes, int n_in,
                              void* d_out, int out_size, void* d_ws, size_t ws_size,
                              hipStream_t stream) {
  const float* w0 = (const float*)d_in[0];  // 1024x1024
  const float* w1 = (const float*)d_in[1];  // 1024x1024
  const float* w2 = (const float*)d_in[2];  // 1024x512
  const float* w3 = (const float*)d_in[3];  // 512x256
  const float* w4 = (const float*)d_in[4];  // 256x128
  const float* spikes = (const float*)d_in[5];  // (128, 1024, 256)

  uint8_t* ws = (uint8_t*)d_ws;
  u16* S0 = (u16*)(ws + 0);            // 64 MiB (input spikes^T / shift ping)
  u16* S1 = (u16*)(ws + 67108864);     // 64 MiB (shift pong)
  u16* Cb = (u16*)(ws + 134217728);    // 64 MiB (bf16 current, reused per layer)
  u16* W0 = (u16*)(ws + 201326592);    // 2 MiB
  u16* W1 = (u16*)(ws + 203423744);    // 2 MiB
  u16* W2 = (u16*)(ws + 205520896);    // 1 MiB
  u16* W3 = (u16*)(ws + 206569472);    // 256 KiB
  u16* W4 = (u16*)(ws + 206831616);    // 64 KiB
  u32* FL = (u32*)(ws + 206897152);    // 64 u32: 4 layers x 16
  u32* F1 = FL +  0;
  u32* F2 = FL + 16;
  u32* F3 = FL + 32;
  u32* F4 = FL + 48;

  float* out0  = (float*)d_out;            // (128,1024,256)
  float* out1  = out0 + 33554432;          // (128,1024,256)
  float* out2  = out0 + 67108864;          // (128, 512,256)
  float* out3  = out0 + 83886080;          // (128, 256,256)
  float* out4  = out0 + 92274688;          // (128, 128,256)
  float* rates = out0 + 96468992;          // (128,128)

  // 1) fused prep: 5 weight transposes + flag zero + input spike transpose
  prep_all<<<2721 + 32768, 256, 0, stream>>>(w0, w1, w2, w3, w4, spikes,
                                             W0, W1, W2, W3, W4, S0, FL);

  // 2) layer pipeline: gemm -> lif, activity-gated per timestep panel
  gemm_bf16<<<256 * 8, 256, 0, stream>>>(S0, W0, Cb, 1024, 1024, nullptr);
  lif_scan<<<512, 256, 0, stream>>>(Cb, nullptr, out0, S1, F1, nullptr, 1024);

  gemm_bf16<<<256 * 8, 256, 0, stream>>>(S1, W1, Cb, 1024, 1024, F1);
  lif_scan<<<512, 256, 0, stream>>>(Cb, F1, out1, S0, F2, nullptr, 1024);

  gemm_bf16<<<256 * 4, 256, 0, stream>>>(S0, W2, Cb, 1024, 512, F2);
  lif_scan<<<256, 256, 0, stream>>>(Cb, F2, out2, S1, F3, nullptr, 512);

  gemm_bf16<<<256 * 2, 256, 0, stream>>>(S1, W3, Cb, 512, 256, F3);
  lif_scan<<<128, 256, 0, stream>>>(Cb, F3, out3, S0, F4, nullptr, 256);

  gemm_bf16<<<256 * 1, 256, 0, stream>>>(S0, W4, Cb, 256, 128, F4);
  lif_scan<<<64, 256, 0, stream>>>(Cb, F4, out4, nullptr, nullptr, rates, 128);
}